// Round 1
// 205.046 us; speedup vs baseline: 1.0510x; 1.0510x over previous
//
#include <hip/hip_runtime.h>
#include <stdint.h>

// Problem constants
#define LDIM 256
#define CDIM 20
#define LC   5120      // L*C
#define NB   1024      // batch
#define BM   128       // i-tile rows
#define BN   256       // batch tile
#define ITOT64 1640    // sum_it (80 - 2*it): 64-K iters per b-col
// exact identities: kstart(it) = 128*it = i0 ; iters64(it) = 80 - 2*it

typedef __attribute__((ext_vector_type(8))) short short8;       // 8 bf16 (4 VGPR)
typedef __attribute__((ext_vector_type(4))) float float4v;      // MFMA acc
typedef __attribute__((ext_vector_type(4))) unsigned int uint4v;
typedef unsigned short ushort_t;

#define XB_BYTES (10485760ull)            // 1024*5120*2
#define WS_NEED  (XB_BYTES)

// round-to-nearest-even fp32 -> bf16, packed pair
__device__ inline uint32_t pack_bf16x2(float a, float b) {
    uint32_t ua = __float_as_uint(a);
    uint32_t ub = __float_as_uint(b);
    ua += 0x7fffu + ((ua >> 16) & 1u);
    ub += 0x7fffu + ((ub >> 16) & 1u);
    return (ua >> 16) | (ub & 0xffff0000u);
}

__device__ inline float bf16_to_f32(ushort_t u) {
    return __uint_as_float(((uint32_t)u) << 16);
}

// async global->LDS 16B; lds base wave-uniform (HW: base + lane*16)
__device__ inline void load_lds16(const void* g, void* l) {
    __builtin_amdgcn_global_load_lds(
        (const __attribute__((address_space(1))) uint32_t*)g,
        (__attribute__((address_space(3))) uint32_t*)l, 16, 0, 0);
}

// ---------------------------------------------------------------------------
// X pass: X fp32 -> bf16 into Xb, fused out[b] = theta0 + dot(theta_lc, x[b,:])
// (T conversion is now fused into pair_fused — no Tb round-trip.)
// ---------------------------------------------------------------------------
__global__ __launch_bounds__(256) void xconv_kernel(
    const float* __restrict__ X, const float* __restrict__ th0,
    const float* __restrict__ thlc, ushort_t* __restrict__ Xb,
    float* __restrict__ out)
{
    const int b = blockIdx.x;
    const int t = threadIdx.x;
    __shared__ float red[4];

    const float*  src = X  + (size_t)b * LC;
    ushort_t*     dst = Xb + (size_t)b * LC;
    float s = 0.f;
    for (int c = t * 4; c < LC; c += 1024) {
        float4 f = *(const float4*)(src + c);
        float4 w = *(const float4*)(thlc + c);
        s += f.x * w.x + f.y * w.y + f.z * w.z + f.w * w.w;
        uint2 u;
        u.x = pack_bf16x2(f.x, f.y);
        u.y = pack_bf16x2(f.z, f.w);
        *(uint2*)(dst + c) = u;
    }
    s += __shfl_xor(s, 1);  s += __shfl_xor(s, 2);  s += __shfl_xor(s, 4);
    s += __shfl_xor(s, 8);  s += __shfl_xor(s, 16); s += __shfl_xor(s, 32);
    if ((t & 63) == 0) red[t >> 6] = s;
    __syncthreads();
    if (t == 0) out[b] = th0[0] + red[0] + red[1] + red[2] + red[3];
}

// ---------------------------------------------------------------------------
// Pair kernel v5: 128x256 tile, BK=64 single-buffer stage.
//  - A operand: fused fp32->bf16 conversion. Reg-staged from T (8x dwordx4 per
//    thread, issued FIRST so the pack's s_waitcnt is vmcnt(8) and B's DMA stays
//    in flight), packed, then swizzled ds_write_b128 (conflict-free: each
//    8-lane group writes one row's permuted 128 B).
//  - B operand: global_load_lds DMA from bf16 Xb (pre-swizzled source addrs).
//  - kblk->XCD grouping: 4 bcol-siblings of a kblk reuse the same fp32 T slab
//    in their XCD's L2.
// 512 blocks, all co-resident (2/CU).
// ---------------------------------------------------------------------------
__global__ __launch_bounds__(256, 2) void pair_fused(
    const float* __restrict__ T, const ushort_t* __restrict__ Xb,
    float* __restrict__ out)
{
    const int n    = blockIdx.x;
    // XCD = n % 8 (round-robin heuristic). Same-XCD blocks share 16 kblks x
    // 4 bcols; the 4 bcol-siblings of a kblk reuse identical T slabs in L2.
    const int kblk = (n & 7) | (((n >> 5) & 15) << 3);   // 0..127
    const int bn0  = ((n >> 3) & 3) * BN;

    const int gbeg = (ITOT64 * kblk) >> 7;
    const int gend = (ITOT64 * (kblk + 1)) >> 7;

    // locate starting segment
    int it = 0, pre = 0;
    while (pre + (80 - 2 * it) <= gbeg) { pre += 80 - 2 * it; ++it; }
    int li = gbeg - pre;

    // LDS: chunk(row, slot) = row*8 + slot, 16 B/chunk; slot = g ^ (row&7)
    __shared__ __align__(16) ushort_t A_s[1024 * 8];   // 16 KB (128 rows x 8 granules)
    __shared__ __align__(16) ushort_t B_s[2048 * 8];   // 32 KB (256 rows x 8 granules)

    const int t    = threadIdx.x;
    const int lane = t & 63;
    const int wid  = t >> 6;
    const int wm   = (wid >> 1) * 64;        // wave i-offset
    const int wn   = (wid & 1) * 128;        // wave b-offset
    const int l16  = lane & 15;
    const int qk   = lane >> 4;              // k-quad within a 32-K MFMA step

    // ---- A staging constants (reg path): thread owns granule ga of rows
    //      r32 + j*32 (j=0..3). Load 2x float4 (32 B) per row, pack to 16 B,
    //      one ds_write_b128 to the swizzled chunk.
    const int r32 = t >> 3;                  // base row 0..31
    const int ga  = t & 7;                   // granule 0..7
    uint32_t offTa[4];                       // element offset within A tile
    int      wAdr[4];                        // LDS byte addr (swizzled)
    #pragma unroll
    for (int j = 0; j < 4; ++j) {
        const int row = r32 + j * 32;
        offTa[j] = (uint32_t)row * LC + (ga << 3);
        wAdr[j]  = ((row << 3) + (ga ^ (row & 7))) << 4;
    }

    // ---- B DMA lane constants (pre-swizzled global source addresses)
    uint32_t offB[8];
    #pragma unroll
    for (int j = 0; j < 8; ++j) {
        const int c = (wid << 9) + (j << 6) + lane;
        const int row = c >> 3;
        const int g = (c & 7) ^ (row & 7);
        offB[j] = (uint32_t)(bn0 + row) * LC + (g << 3);
    }

    // ---- LDS fragment read byte-addresses (all 24 precomputed, loop-invariant)
    int adrA[2][4], adrB[2][8];
    #pragma unroll
    for (int step = 0; step < 2; ++step) {
        const int kf = step * 4 + qk;        // granule 0..7
        #pragma unroll
        for (int mt = 0; mt < 4; ++mt) {
            const int r = wm + mt * 16 + l16;
            adrA[step][mt] = ((r << 3) + (kf ^ (r & 7))) << 4;
        }
        #pragma unroll
        for (int nt = 0; nt < 8; ++nt) {
            const int r = wn + nt * 16 + l16;
            adrB[step][nt] = ((r << 3) + (kf ^ (r & 7))) << 4;
        }
    }

    int i0 = it << 7;
    int k0 = i0 + (li << 6);                 // kstart + li*64

    float4v acc[4][8];
    #pragma unroll
    for (int mt = 0; mt < 4; ++mt)
        #pragma unroll
        for (int nt = 0; nt < 8; ++nt)
            #pragma unroll
            for (int r = 0; r < 4; ++r) acc[mt][nt][r] = 0.f;

    for (int g = gbeg; g < gend; ++g) {
        __syncthreads();                     // prior fragment reads done

        // A fp32 loads FIRST (pack waits on these with vmcnt(8): B stays in flight)
        const float* Tbase = T + (size_t)i0 * LC + k0;
        float4 a0[4], a1[4];
        #pragma unroll
        for (int j = 0; j < 4; ++j) {
            a0[j] = *(const float4*)(Tbase + offTa[j]);
            a1[j] = *(const float4*)(Tbase + offTa[j] + 4);
        }
        // B DMA (fire-and-forget into LDS)
        #pragma unroll
        for (int j = 0; j < 8; ++j)
            load_lds16(Xb + k0 + offB[j], B_s + (((wid << 9) + (j << 6)) << 3));
        // pack + swizzled LDS write
        #pragma unroll
        for (int j = 0; j < 4; ++j) {
            uint4v v;
            v[0] = pack_bf16x2(a0[j].x, a0[j].y);
            v[1] = pack_bf16x2(a0[j].z, a0[j].w);
            v[2] = pack_bf16x2(a1[j].x, a1[j].y);
            v[3] = pack_bf16x2(a1[j].z, a1[j].w);
            *(uint4v*)((char*)A_s + wAdr[j]) = v;
        }
        __syncthreads();                     // drains vmcnt(0)+lgkmcnt(0)

        #pragma unroll
        for (int step = 0; step < 2; ++step) {
            short8 af[4], bfr[8];
            #pragma unroll
            for (int mt = 0; mt < 4; ++mt)
                af[mt] = *(const short8*)((const char*)A_s + adrA[step][mt]);
            #pragma unroll
            for (int nt = 0; nt < 8; ++nt)
                bfr[nt] = *(const short8*)((const char*)B_s + adrB[step][nt]);
            #pragma unroll
            for (int mt = 0; mt < 4; ++mt)
                #pragma unroll
                for (int nt = 0; nt < 8; ++nt)
                    acc[mt][nt] = __builtin_amdgcn_mfma_f32_16x16x32_bf16(
                        af[mt], bfr[nt], acc[mt][nt], 0, 0, 0);
        }

        ++li;
        const bool segEnd = (li == 80 - 2 * it);
        if (segEnd || g + 1 == gend) {
            // epilogue flush: out[b] += sum_i x[b,i] * D[i,b], x from bf16 Xb
            #pragma unroll
            for (int nt = 0; nt < 8; ++nt) {
                const int b = bn0 + wn + nt * 16 + l16;
                const ushort_t* xb = Xb + (size_t)b * LC + i0 + wm + qk * 4;
                float s = 0.f;
                #pragma unroll
                for (int mt = 0; mt < 4; ++mt) {
                    ushort4 xv = *(const ushort4*)(xb + mt * 16);
                    s += acc[mt][nt][0] * bf16_to_f32(xv.x)
                       + acc[mt][nt][1] * bf16_to_f32(xv.y)
                       + acc[mt][nt][2] * bf16_to_f32(xv.z)
                       + acc[mt][nt][3] * bf16_to_f32(xv.w);
                }
                s += __shfl_xor(s, 16);      // reduce the 4 k-quads (same b)
                s += __shfl_xor(s, 32);
                if (qk == 0) atomicAdd(&out[b], s);
            }
            #pragma unroll
            for (int mt = 0; mt < 4; ++mt)
                #pragma unroll
                for (int nt = 0; nt < 8; ++nt)
                    #pragma unroll
                    for (int r = 0; r < 4; ++r) acc[mt][nt][r] = 0.f;
        }
        if (segEnd) {
            ++it; li = 0;
            if (it < 40) {
                i0 = it << 7;
                k0 = i0;
            }
        } else {
            k0 += 64;
        }
    }
}

// ===========================================================================
// Fallback (ws too small): proven R2 path, fp32 staging from global.
// ===========================================================================
__global__ __launch_bounds__(256) void init_kernel(
    const float* __restrict__ x, const float* __restrict__ th0,
    const float* __restrict__ thlc, float* __restrict__ out)
{
    const int b = blockIdx.x;
    const float4* xb = (const float4*)(x + (size_t)b * LC);
    const float4* tv = (const float4*)thlc;
    float s = 0.f;
    for (int i = threadIdx.x; i < LC / 4; i += 256) {
        float4 a = xb[i], t = tv[i];
        s += a.x * t.x + a.y * t.y + a.z * t.z + a.w * t.w;
    }
    s += __shfl_xor(s, 1);  s += __shfl_xor(s, 2);  s += __shfl_xor(s, 4);
    s += __shfl_xor(s, 8);  s += __shfl_xor(s, 16); s += __shfl_xor(s, 32);
    __shared__ float red[4];
    if ((threadIdx.x & 63) == 0) red[threadIdx.x >> 6] = s;
    __syncthreads();
    if (threadIdx.x == 0) out[b] = th0[0] + red[0] + red[1] + red[2] + red[3];
}

__global__ __launch_bounds__(256) void pair_kernel(
    const float* __restrict__ T, const float* __restrict__ X,
    float* __restrict__ out)
{
    const int n  = blockIdx.x;
    const int r  = n & 7;
    const int g  = n >> 3;
    const int i0  = (g >> 3) * BM;
    const int bn0 = (g & 7) * 128;
    const int kstart = i0;
    const int nIter  = (LC - kstart) >> 6;
    const int ipc    = (nIter + 7) >> 3;
    const int itBeg  = r * ipc;
    const int itEnd  = (itBeg + ipc < nIter) ? (itBeg + ipc) : nIter;
    if (itBeg >= itEnd) return;
    const int kbeg   = kstart + (itBeg << 6);

    __shared__ __align__(16) short A_s[8 * BM * 8];
    __shared__ __align__(16) short B_s[8 * BM * 8];

    const int t    = threadIdx.x;
    const int lane = t & 63;
    const int wid  = t >> 6;
    const int wm   = (wid >> 1) * 64;
    const int wn   = (wid & 1) * 64;
    const int l16  = lane & 15;
    const int qk   = lane >> 4;

    const float* pA[4]; const float* pB[4]; int sIdx[4];
    #pragma unroll
    for (int u = 0; u < 4; ++u) {
        const int id  = t + u * 256;
        const int row = id >> 3;
        const int kq  = id & 7;
        pA[u] = T + (size_t)(i0 + row) * LC + kbeg + kq * 8;
        pB[u] = X + (size_t)(bn0 + row) * LC + kbeg + kq * 8;
        sIdx[u] = (kq * BM + (row ^ kq)) * 8;
    }

    float4v acc[4][4] = {};
    for (int itr = itBeg; itr < itEnd; ++itr) {
        __syncthreads();
        #pragma unroll
        for (int u = 0; u < 4; ++u) {
            float4 a0 = ((const float4*)pA[u])[0];
            float4 a1 = ((const float4*)pA[u])[1];
            float4 b0 = ((const float4*)pB[u])[0];
            float4 b1 = ((const float4*)pB[u])[1];
            pA[u] += 64; pB[u] += 64;
            uint4v va, vb;
            va[0] = pack_bf16x2(a0.x, a0.y); va[1] = pack_bf16x2(a0.z, a0.w);
            va[2] = pack_bf16x2(a1.x, a1.y); va[3] = pack_bf16x2(a1.z, a1.w);
            vb[0] = pack_bf16x2(b0.x, b0.y); vb[1] = pack_bf16x2(b0.z, b0.w);
            vb[2] = pack_bf16x2(b1.x, b1.y); vb[3] = pack_bf16x2(b1.z, b1.w);
            *(uint4v*)(A_s + sIdx[u]) = va;
            *(uint4v*)(B_s + sIdx[u]) = vb;
        }
        __syncthreads();
        #pragma unroll
        for (int step = 0; step < 2; ++step) {
            const int kf = step * 4 + qk;
            short8 af[4], bfr[4];
            #pragma unroll
            for (int mt = 0; mt < 4; ++mt)
                af[mt] = *(const short8*)(A_s + (kf * BM + ((wm + mt * 16 + l16) ^ kf)) * 8);
            #pragma unroll
            for (int nt = 0; nt < 4; ++nt)
                bfr[nt] = *(const short8*)(B_s + (kf * BM + ((wn + nt * 16 + l16) ^ kf)) * 8);
            #pragma unroll
            for (int mt = 0; mt < 4; ++mt)
                #pragma unroll
                for (int nt = 0; nt < 4; ++nt)
                    acc[mt][nt] = __builtin_amdgcn_mfma_f32_16x16x32_bf16(
                        af[mt], bfr[nt], acc[mt][nt], 0, 0, 0);
        }
    }
    #pragma unroll
    for (int nt = 0; nt < 4; ++nt) {
        const int b = bn0 + wn + nt * 16 + l16;
        const float* xb = X + (size_t)b * LC + i0 + wm + qk * 4;
        float s = 0.f;
        #pragma unroll
        for (int mt = 0; mt < 4; ++mt) {
            float4 xv = *(const float4*)(xb + mt * 16);
            s += acc[mt][nt][0] * xv.x + acc[mt][nt][1] * xv.y +
                 acc[mt][nt][2] * xv.z + acc[mt][nt][3] * xv.w;
        }
        s += __shfl_xor(s, 16);
        s += __shfl_xor(s, 32);
        if (qk == 0) atomicAdd(&out[b], s);
    }
}

extern "C" void kernel_launch(void* const* d_in, const int* in_sizes, int n_in,
                              void* d_out, int out_size, void* d_ws, size_t ws_size,
                              hipStream_t stream) {
    const float* x    = (const float*)d_in[0];   // (B, L, C) fp32
    const float* th0  = (const float*)d_in[1];   // (1,)
    const float* thlc = (const float*)d_in[2];   // (1, L, C)
    const float* T    = (const float*)d_in[3];   // (1, L, C, L, C) — pre-masked
    float* out = (float*)d_out;                  // (B, 1) fp32

    if (ws_size >= WS_NEED) {
        ushort_t* Xb = (ushort_t*)d_ws;
        xconv_kernel<<<NB, 256, 0, stream>>>(x, th0, thlc, Xb, out);
        pair_fused<<<512, 256, 0, stream>>>(T, Xb, out);
    } else {
        init_kernel<<<NB, 256, 0, stream>>>(x, th0, thlc, out);
        pair_kernel<<<(LC / BM) * (NB / 128) * 8, 256, 0, stream>>>(T, x, out);
    }
}